// Round 1
// baseline (374.938 us; speedup 1.0000x reference)
//
#include <hip/hip_runtime.h>

#define HW 16384
#define NC 16      // C selected classes
#define NG 32      // G groups (512 / 16)
#define NPAIR 120  // C*(C-1)/2

// ---------------------------------------------------------------------------
// Kernel 1: per-class top-32 channels by |w| (descending, stable ties by
// smaller index, matching jnp.argsort(-w)) + sigmoid(|w|) weights.
// One wave per class (16 waves). Also zeroes d_out (harness poisons it).
// ---------------------------------------------------------------------------
__global__ __launch_bounds__(1024) void topk_kernel(const float* __restrict__ W,
                                                    int* __restrict__ chan,
                                                    float* __restrict__ wgt,
                                                    float* __restrict__ out) {
    const int wave = threadIdx.x >> 6;  // class 0..15
    const int lane = threadIdx.x & 63;
    if (threadIdx.x == 0) out[0] = 0.0f;

    // lane holds channels lane + 64*j, j = 0..7  (512 channels)
    float v[8];
#pragma unroll
    for (int j = 0; j < 8; ++j)
        v[j] = fabsf(W[wave * 512 + lane + 64 * j]);

    for (int it = 0; it < NG; ++it) {
        // local argmax (ascending j => smallest index wins ties)
        float best = -1.0f;
        int bidx = 0;
#pragma unroll
        for (int j = 0; j < 8; ++j) {
            if (v[j] > best) { best = v[j]; bidx = lane + 64 * j; }
        }
        // wave-wide argmax butterfly; tie -> smaller channel index
#pragma unroll
        for (int off = 1; off < 64; off <<= 1) {
            float ob = __shfl_xor(best, off);
            int   oi = __shfl_xor(bidx, off);
            if (ob > best || (ob == best && oi < bidx)) { best = ob; bidx = oi; }
        }
        if (lane == 0) {
            chan[wave * NG + it] = bidx;
            wgt[wave * NG + it] = 1.0f / (1.0f + expf(-best));
        }
        // knock out the winner
#pragma unroll
        for (int j = 0; j < 8; ++j)
            if (bidx == lane + 64 * j) v[j] = -1.0f;
    }
}

// ---------------------------------------------------------------------------
// Kernel 2: one block per (b, g). Stream 16 gathered channel rows, accumulate
// all 120 pairwise dot products in registers, reduce, clamp, atomicAdd.
// ---------------------------------------------------------------------------
__global__ __launch_bounds__(256) void cov_kernel(const float* __restrict__ x,
                                                  const int* __restrict__ chan,
                                                  const float* __restrict__ wgt,
                                                  float* __restrict__ out) {
    const int blk = blockIdx.x;   // 0..255
    const int b = blk >> 5;       // batch
    const int g = blk & 31;       // group
    const int t = threadIdx.x;

    // wave-uniform channel base pointers -> SALU addressing
    const float* ptr[NC];
#pragma unroll
    for (int c = 0; c < NC; ++c) {
        int ch = __builtin_amdgcn_readfirstlane(chan[c * NG + g]);
        ptr[c] = x + ((size_t)(b * 512 + ch) << 14);  // * HW
    }

    float acc[NPAIR];
#pragma unroll
    for (int p = 0; p < NPAIR; ++p) acc[p] = 0.0f;

    // 16384 h split: iter it covers h in [it*1024, it*1024+1024), 4 h/thread
    for (int it = 0; it < 16; ++it) {
        const int h = it * 1024 + t * 4;
        float4 v[NC];
#pragma unroll
        for (int c = 0; c < NC; ++c)
            v[c] = *(const float4*)(ptr[c] + h);
        int p = 0;
#pragma unroll
        for (int c = 0; c < NC; ++c) {
#pragma unroll
            for (int d = c + 1; d < NC; ++d) {
                acc[p] += v[c].x * v[d].x;
                acc[p] += v[c].y * v[d].y;
                acc[p] += v[c].z * v[d].z;
                acc[p] += v[c].w * v[d].w;
                ++p;
            }
        }
    }

    // per-pair wave allreduce (butterfly)
#pragma unroll
    for (int p = 0; p < NPAIR; ++p) {
        float s = acc[p];
#pragma unroll
        for (int off = 1; off < 64; off <<= 1) s += __shfl_xor(s, off);
        acc[p] = s;
    }

    __shared__ float red[4][NPAIR];
    __shared__ float contrib[NPAIR];
    const int wave = t >> 6;
    const int lane = t & 63;
    if (lane == 0) {
#pragma unroll
        for (int p = 0; p < NPAIR; ++p) red[wave][p] = acc[p];
    }
    __syncthreads();

    if (t < NPAIR) {
        float s = red[0][t] + red[1][t] + red[2][t] + red[3][t];
        // decode linear pair index -> (c, d), row-major strict upper
        int c = 0, rem = t;
        while (rem >= 15 - c) { rem -= 15 - c; ++c; }
        int d = c + 1 + rem;
        contrib[t] = fabsf(s) * wgt[c * NG + g] * wgt[d * NG + g];
    }
    __syncthreads();

    if (t == 0) {
        float tot = 0.0f;
        for (int p = 0; p < NPAIR; ++p) tot += contrib[p];
        // cov entries scaled by 1/(HW-1); EPS*I only touches the diagonal,
        // which the strict-upper mask excludes.
        float off = tot * (1.0f / 16383.0f) - 60.0f;   // margin = floor(120/2)
        float loss = fmaxf(off * (1.0f / 120.0f), 0.0f);
        atomicAdd(out, loss * 0.125f);                 // / B, B = 8
    }
}

extern "C" void kernel_launch(void* const* d_in, const int* in_sizes, int n_in,
                              void* d_out, int out_size, void* d_ws, size_t ws_size,
                              hipStream_t stream) {
    const float* x = (const float*)d_in[0];          // [8, 512, 128, 128]
    const float* W = (const float*)d_in[1];          // [19, 512]
    float* out = (float*)d_out;                      // [1]

    int*   chan = (int*)d_ws;                        // [16][32]
    float* wgt  = (float*)((char*)d_ws + 512 * sizeof(int));  // [16][32]

    topk_kernel<<<1, 1024, 0, stream>>>(W, chan, wgt, out);
    cov_kernel<<<256, 256, 0, stream>>>(x, chan, wgt, out);
}